// Round 1
// baseline (887.426 us; speedup 1.0000x reference)
//
#include <hip/hip_runtime.h>

#define D 64

// One wave (64 lanes) per edge; lane = feature dim.
__global__ void fwd_scatter(const float* __restrict__ feat_src,
                            const int* __restrict__ edge_src,
                            const int* __restrict__ edge_dst,
                            float* __restrict__ rst,
                            float* __restrict__ deg_dst,
                            int E) {
    int e = blockIdx.x * 4 + (threadIdx.x >> 6);
    int lane = threadIdx.x & 63;
    if (e >= E) return;
    int s = edge_src[e];
    int d = edge_dst[e];
    float v = feat_src[(size_t)s * D + lane];
    atomicAdd(&rst[(size_t)d * D + lane], v);
    if (lane == 0) atomicAdd(&deg_dst[d], 1.0f);
}

// One wave per dst node: 4 scaled-dot scores -> softmax -> weighted pf sum.
__global__ void attn_norm(float* __restrict__ rst,
                          const float* __restrict__ pf,
                          const float* __restrict__ deg_dst,
                          int n_dst) {
    int n = blockIdx.x * 4 + (threadIdx.x >> 6);
    int lane = threadIdx.x & 63;
    if (n >= n_dst) return;
    float r = rst[(size_t)n * D + lane];
    const float* p = pf + (size_t)n * 4 * D + lane;
    float p0 = p[0 * D], p1 = p[1 * D], p2 = p[2 * D], p3 = p[3 * D];
    float s0 = r * p0, s1 = r * p1, s2 = r * p2, s3 = r * p3;
    #pragma unroll
    for (int off = 32; off >= 1; off >>= 1) {
        s0 += __shfl_xor(s0, off);
        s1 += __shfl_xor(s1, off);
        s2 += __shfl_xor(s2, off);
        s3 += __shfl_xor(s3, off);
    }
    // scores / d_sqrt (8.0)
    s0 *= 0.125f; s1 *= 0.125f; s2 *= 0.125f; s3 *= 0.125f;
    float m = fmaxf(fmaxf(s0, s1), fmaxf(s2, s3));
    float e0 = expf(s0 - m), e1 = expf(s1 - m), e2 = expf(s2 - m), e3 = expf(s3 - m);
    float inv = 1.0f / (e0 + e1 + e2 + e3);
    float patt = (e0 * p0 + e1 * p1 + e2 * p2 + e3 * p3) * inv;
    float out = (r + 0.1f * tanhf(patt)) / fmaxf(deg_dst[n], 1.0f);
    rst[(size_t)n * D + lane] = out;
}

// Reverse scatter: bsrc[src] += rst[dst], plus out-degree count.
__global__ void bwd_scatter(const float* __restrict__ rst,
                            const int* __restrict__ edge_src,
                            const int* __restrict__ edge_dst,
                            float* __restrict__ bsrc,
                            float* __restrict__ deg_src,
                            int E) {
    int e = blockIdx.x * 4 + (threadIdx.x >> 6);
    int lane = threadIdx.x & 63;
    if (e >= E) return;
    int s = edge_src[e];
    int d = edge_dst[e];
    float v = rst[(size_t)d * D + lane];
    atomicAdd(&bsrc[(size_t)s * D + lane], v);
    if (lane == 0) atomicAdd(&deg_src[s], 1.0f);
}

// bsrc[i] /= max(deg_src[row], 1)
__global__ void norm_src(float* __restrict__ bsrc,
                         const float* __restrict__ deg_src,
                         int n_src) {
    int i = blockIdx.x * blockDim.x + threadIdx.x;  // one float4 per thread
    int total = n_src * (D / 4);
    if (i >= total) return;
    int row = i / (D / 4);
    float invd = 1.0f / fmaxf(deg_src[row], 1.0f);
    float4 v = ((const float4*)bsrc)[i];
    v.x *= invd; v.y *= invd; v.z *= invd; v.w *= invd;
    ((float4*)bsrc)[i] = v;
}

extern "C" void kernel_launch(void* const* d_in, const int* in_sizes, int n_in,
                              void* d_out, int out_size, void* d_ws, size_t ws_size,
                              hipStream_t stream) {
    const float* feat_src = (const float*)d_in[0];
    // d_in[1] (feat_dst) is only used for its shape in the reference.
    const float* pf       = (const float*)d_in[2];
    const int*   edge_src = (const int*)d_in[3];
    const int*   edge_dst = (const int*)d_in[4];

    int n_src = in_sizes[0] / D;
    int n_dst = in_sizes[1] / D;
    int E     = in_sizes[3];

    float* bsrc = (float*)d_out;                         // [n_src, D]
    float* rst  = (float*)d_out + (size_t)n_src * D;     // [n_dst, D]
    float* deg_dst = (float*)d_ws;                       // [n_dst]
    float* deg_src = deg_dst + n_dst;                    // [n_src]

    hipMemsetAsync(d_out, 0, (size_t)out_size * sizeof(float), stream);
    hipMemsetAsync(d_ws, 0, (size_t)(n_dst + n_src) * sizeof(float), stream);

    fwd_scatter<<<(E + 3) / 4, 256, 0, stream>>>(feat_src, edge_src, edge_dst,
                                                 rst, deg_dst, E);
    attn_norm<<<(n_dst + 3) / 4, 256, 0, stream>>>(rst, pf, deg_dst, n_dst);
    bwd_scatter<<<(E + 3) / 4, 256, 0, stream>>>(rst, edge_src, edge_dst,
                                                 bsrc, deg_src, E);
    norm_src<<<(n_src * (D / 4) + 255) / 256, 256, 0, stream>>>(bsrc, deg_src, n_src);
}

// Round 2
// 670.153 us; speedup vs baseline: 1.3242x; 1.3242x over previous
//
#include <hip/hip_runtime.h>

#define D 64

// ============ CSR build ============

__global__ void hist_kernel(const int* __restrict__ es, const int* __restrict__ ed,
                            int* __restrict__ cnt_dst, int* __restrict__ cnt_src, int E) {
    int e = blockIdx.x * blockDim.x + threadIdx.x;
    if (e >= E) return;
    atomicAdd(&cnt_dst[ed[e]], 1);
    atomicAdd(&cnt_src[es[e]], 1);
}

// Phase A: per-1024-element chunk sums
__global__ void scan_partial(const int* __restrict__ cnt, int* __restrict__ part, int n) {
    int t = threadIdx.x;
    int base = blockIdx.x * 1024;
    int v = 0;
    #pragma unroll
    for (int k = 0; k < 4; ++k) {
        int i = base + k * 256 + t;
        if (i < n) v += cnt[i];
    }
    #pragma unroll
    for (int off = 32; off >= 1; off >>= 1) v += __shfl_down(v, off);
    __shared__ int wsum[4];
    if ((t & 63) == 0) wsum[t >> 6] = v;
    __syncthreads();
    if (t == 0) part[blockIdx.x] = wsum[0] + wsum[1] + wsum[2] + wsum[3];
}

// Phase B: single-block exclusive scan of <=256 partials
__global__ void scan_exclusive_part(int* part, int nb) {
    __shared__ int sh[256];
    int t = threadIdx.x;
    int v = (t < nb) ? part[t] : 0;
    sh[t] = v;
    __syncthreads();
    for (int off = 1; off < 256; off <<= 1) {
        int x = (t >= off) ? sh[t - off] : 0;
        __syncthreads();
        sh[t] += x;
        __syncthreads();
    }
    if (t < nb) part[t] = sh[t] - v;  // exclusive
}

// Phase C: per-chunk exclusive scan + chunk offset -> row offsets (and a copy for fill positions)
__global__ void scan_final(const int* __restrict__ cnt, const int* __restrict__ part,
                           int* __restrict__ ro, int* __restrict__ pos, int n) {
    int t = threadIdx.x;
    int base = blockIdx.x * 1024;
    int v[4];
    int tsum = 0;
    #pragma unroll
    for (int k = 0; k < 4; ++k) {
        int i = base + t * 4 + k;
        v[k] = (i < n) ? cnt[i] : 0;
        tsum += v[k];
    }
    __shared__ int sh[256];
    sh[t] = tsum;
    __syncthreads();
    for (int off = 1; off < 256; off <<= 1) {
        int x = (t >= off) ? sh[t - off] : 0;
        __syncthreads();
        sh[t] += x;
        __syncthreads();
    }
    int acc = sh[t] - tsum + part[blockIdx.x];  // global exclusive prefix for first elem
    #pragma unroll
    for (int k = 0; k < 4; ++k) {
        int i = base + t * 4 + k;
        if (i < n) {
            ro[i] = acc;
            pos[i] = acc;
            if (i == n - 1) ro[n] = acc + v[k];
            acc += v[k];
        }
    }
}

// Bucket fill: vals_dst[.] = src id (grouped by dst), vals_src[.] = dst id (grouped by src)
__global__ void fill_kernel(const int* __restrict__ es, const int* __restrict__ ed,
                            int* __restrict__ pos_dst, int* __restrict__ pos_src,
                            int* __restrict__ vals_dst, int* __restrict__ vals_src, int E) {
    int e = blockIdx.x * blockDim.x + threadIdx.x;
    if (e >= E) return;
    int s = es[e], d = ed[e];
    vals_dst[atomicAdd(&pos_dst[d], 1)] = s;
    vals_src[atomicAdd(&pos_src[s], 1)] = d;
}

// ============ Aggregation ============

// One wave per dst node: gather-sum feat_src rows, then fused attention + degree norm.
__global__ void fwd_gather_attn(const float* __restrict__ feat_src,
                                const float* __restrict__ pf,
                                const int* __restrict__ ro, const int* __restrict__ vals,
                                float* __restrict__ rst, int n_dst) {
    int n = blockIdx.x * 4 + (threadIdx.x >> 6);
    int lane = threadIdx.x & 63;
    if (n >= n_dst) return;
    int beg = ro[n], end = ro[n + 1];
    float acc = 0.f;
    int j = beg;
    for (; j + 4 <= end; j += 4) {
        int s0 = vals[j], s1 = vals[j + 1], s2 = vals[j + 2], s3 = vals[j + 3];
        acc += feat_src[(size_t)s0 * D + lane];
        acc += feat_src[(size_t)s1 * D + lane];
        acc += feat_src[(size_t)s2 * D + lane];
        acc += feat_src[(size_t)s3 * D + lane];
    }
    for (; j < end; ++j) acc += feat_src[(size_t)vals[j] * D + lane];

    // attention over K=4 pretrained views
    const float* p = pf + (size_t)n * 4 * D + lane;
    float p0 = p[0], p1 = p[D], p2 = p[2 * D], p3 = p[3 * D];
    float s0 = acc * p0, s1 = acc * p1, s2 = acc * p2, s3 = acc * p3;
    #pragma unroll
    for (int off = 32; off >= 1; off >>= 1) {
        s0 += __shfl_xor(s0, off);
        s1 += __shfl_xor(s1, off);
        s2 += __shfl_xor(s2, off);
        s3 += __shfl_xor(s3, off);
    }
    s0 *= 0.125f; s1 *= 0.125f; s2 *= 0.125f; s3 *= 0.125f;
    float m = fmaxf(fmaxf(s0, s1), fmaxf(s2, s3));
    float e0 = expf(s0 - m), e1 = expf(s1 - m), e2 = expf(s2 - m), e3 = expf(s3 - m);
    float inv = 1.0f / (e0 + e1 + e2 + e3);
    float patt = (e0 * p0 + e1 * p1 + e2 * p2 + e3 * p3) * inv;
    float out = (acc + 0.1f * tanhf(patt)) / fmaxf((float)(end - beg), 1.0f);
    rst[(size_t)n * D + lane] = out;
}

// One wave per src node: gather-sum rst rows, fused out-degree norm.
__global__ void bwd_gather(const float* __restrict__ rst,
                           const int* __restrict__ ro, const int* __restrict__ vals,
                           float* __restrict__ bsrc, int n_src) {
    int n = blockIdx.x * 4 + (threadIdx.x >> 6);
    int lane = threadIdx.x & 63;
    if (n >= n_src) return;
    int beg = ro[n], end = ro[n + 1];
    float acc = 0.f;
    int j = beg;
    for (; j + 4 <= end; j += 4) {
        int d0 = vals[j], d1 = vals[j + 1], d2 = vals[j + 2], d3 = vals[j + 3];
        acc += rst[(size_t)d0 * D + lane];
        acc += rst[(size_t)d1 * D + lane];
        acc += rst[(size_t)d2 * D + lane];
        acc += rst[(size_t)d3 * D + lane];
    }
    for (; j < end; ++j) acc += rst[(size_t)vals[j] * D + lane];
    bsrc[(size_t)n * D + lane] = acc / fmaxf((float)(end - beg), 1.0f);
}

extern "C" void kernel_launch(void* const* d_in, const int* in_sizes, int n_in,
                              void* d_out, int out_size, void* d_ws, size_t ws_size,
                              hipStream_t stream) {
    const float* feat_src = (const float*)d_in[0];
    const float* pf       = (const float*)d_in[2];
    const int*   edge_src = (const int*)d_in[3];
    const int*   edge_dst = (const int*)d_in[4];

    int n_src = in_sizes[0] / D;
    int n_dst = in_sizes[1] / D;
    int E     = in_sizes[3];

    float* bsrc = (float*)d_out;                      // [n_src, D]
    float* rst  = (float*)d_out + (size_t)n_src * D;  // [n_dst, D]

    // workspace layout (ints), ~13.7 MB total
    int* w = (int*)d_ws;
    int* cnt_dst  = w;  w += n_dst;
    int* cnt_src  = w;  w += n_src;      // cnt_* contiguous -> one memset
    int* ro_dst   = w;  w += n_dst + 1;
    int* ro_src   = w;  w += n_src + 1;
    int* pos_dst  = w;  w += n_dst;
    int* pos_src  = w;  w += n_src;
    int* part_d   = w;  w += 256;
    int* part_s   = w;  w += 256;
    int* vals_dst = w;  w += E;
    int* vals_src = w;  w += E;

    hipMemsetAsync(cnt_dst, 0, (size_t)(n_dst + n_src) * sizeof(int), stream);

    int nb_dst = (n_dst + 1023) / 1024;  // 98
    int nb_src = (n_src + 1023) / 1024;  // 196  (<=256 required by scan_exclusive_part)

    hist_kernel<<<(E + 255) / 256, 256, 0, stream>>>(edge_src, edge_dst, cnt_dst, cnt_src, E);

    scan_partial<<<nb_dst, 256, 0, stream>>>(cnt_dst, part_d, n_dst);
    scan_partial<<<nb_src, 256, 0, stream>>>(cnt_src, part_s, n_src);
    scan_exclusive_part<<<1, 256, 0, stream>>>(part_d, nb_dst);
    scan_exclusive_part<<<1, 256, 0, stream>>>(part_s, nb_src);
    scan_final<<<nb_dst, 256, 0, stream>>>(cnt_dst, part_d, ro_dst, pos_dst, n_dst);
    scan_final<<<nb_src, 256, 0, stream>>>(cnt_src, part_s, ro_src, pos_src, n_src);

    fill_kernel<<<(E + 255) / 256, 256, 0, stream>>>(edge_src, edge_dst, pos_dst, pos_src,
                                                     vals_dst, vals_src, E);

    fwd_gather_attn<<<(n_dst + 3) / 4, 256, 0, stream>>>(feat_src, pf, ro_dst, vals_dst,
                                                         rst, n_dst);
    bwd_gather<<<(n_src + 3) / 4, 256, 0, stream>>>(rst, ro_src, vals_src, bsrc, n_src);
}